// Round 3
// baseline (6605.514 us; speedup 1.0000x reference)
//
#include <hip/hip_runtime.h>
#include <math.h>

#define Lt 512   // timesteps
#define Bn 128   // batch
#define Dd 512   // input dim
#define Hh 512   // hidden dim

typedef __attribute__((ext_vector_type(4))) float f32x4;
typedef __attribute__((ext_vector_type(8))) __bf16 bf16x8;
typedef __attribute__((ext_vector_type(8))) unsigned short u16x8;

__device__ __forceinline__ unsigned short f2bf_rne(float f) {
    unsigned u = __float_as_uint(f);
    u = (u + 0x7FFFu + ((u >> 16) & 1u)) >> 16;  // RNE
    return (unsigned short)u;
}
__device__ __forceinline__ float bf2f(unsigned short s) {
    return __uint_as_float(((unsigned)s) << 16);
}
// tanh via hw exp+rcp; exact saturation at +/-1 for |z| large (inf-safe)
__device__ __forceinline__ float tanh_fast(float z) {
    float e = __expf(2.f * z);
    return 1.f - 2.f * __builtin_amdgcn_rcpf(e + 1.f);
}

// ---------------------------------------------------------------------------
// Zero the 256 per-wg sync slots (d_ws is poisoned 0xAA before every launch).
// ---------------------------------------------------------------------------
__global__ void zero_flags_kernel(unsigned* __restrict__ flags) {
    int i = blockIdx.x * 256 + threadIdx.x;
    if (i < 256) flags[i] = 0;
}

// ---------------------------------------------------------------------------
// xproj = x @ Wx_w^T + Wx_b + Wh_b via MFMA bf16 hi/lo (3 products).
// Tile: 64 m x 16 j per wg; 4 waves, wave w owns rows [m0+16w, m0+16w+16),
// full K=512. Wx j-slice staged in LDS hi/lo (RNE). A trunc-split from global.
// C/D layout (validated R2): col = lane&15 (j), row = quad*4 + reg (m).
// ---------------------------------------------------------------------------
__global__ __launch_bounds__(256) void xproj_mfma_kernel(
    const float* __restrict__ x, const float* __restrict__ Wx,
    const float* __restrict__ biasx, const float* __restrict__ biash,
    float* __restrict__ out) {
    __shared__ unsigned short Whi[16 * 520];
    __shared__ unsigned short Wlo[16 * 520];

    const int tid = threadIdx.x;
    const int jg = blockIdx.x & 31;   // j-group fastest: adjacent wgs share x rows
    const int mt = blockIdx.x >> 5;
    const int j0g = jg * 16;
    const int m0 = mt * 64;

    #pragma unroll
    for (int it = 0; it < 8; ++it) {
        int idx = (it * 256 + tid) * 4;
        int j = idx >> 9;
        int k = idx & 511;
        float4 w = *(const float4*)(Wx + (size_t)(j0g + j) * Dd + k);
        int base = j * 520 + k;
        unsigned short s0 = f2bf_rne(w.x); Whi[base + 0] = s0; Wlo[base + 0] = f2bf_rne(w.x - bf2f(s0));
        unsigned short s1 = f2bf_rne(w.y); Whi[base + 1] = s1; Wlo[base + 1] = f2bf_rne(w.y - bf2f(s1));
        unsigned short s2 = f2bf_rne(w.z); Whi[base + 2] = s2; Wlo[base + 2] = f2bf_rne(w.z - bf2f(s2));
        unsigned short s3 = f2bf_rne(w.w); Whi[base + 3] = s3; Wlo[base + 3] = f2bf_rne(w.w - bf2f(s3));
    }
    __syncthreads();

    const int lane = tid & 63;
    const int wv = tid >> 6;
    const int rw = lane & 15;
    const int quad = lane >> 4;
    const int mrow = m0 + wv * 16 + rw;         // A row this lane feeds
    const unsigned short* WhiR = Whi + rw * 520;
    const unsigned short* WloR = Wlo + rw * 520;

    float bsum = biasx[j0g + rw] + biash[j0g + rw];  // hoisted, hides latency

    f32x4 acc0 = {0.f, 0.f, 0.f, 0.f};
    f32x4 acc1 = {0.f, 0.f, 0.f, 0.f};
    #pragma unroll 4
    for (int c = 0; c < 16; ++c) {
        int kk = c * 32 + quad * 8;
        const float* xp = x + (size_t)mrow * Dd + kk;
        float4 v0 = *(const float4*)xp;
        float4 v1 = *(const float4*)(xp + 4);
        float vv[8] = {v0.x, v0.y, v0.z, v0.w, v1.x, v1.y, v1.z, v1.w};
        u16x8 hi8, lo8;
        #pragma unroll
        for (int i = 0; i < 8; ++i) {
            unsigned u = __float_as_uint(vv[i]);
            unsigned short h = (unsigned short)(u >> 16);        // trunc split
            hi8[i] = h;
            lo8[i] = (unsigned short)(__float_as_uint(vv[i] - bf2f(h)) >> 16);
        }
        bf16x8 aH = __builtin_bit_cast(bf16x8, hi8);
        bf16x8 aL = __builtin_bit_cast(bf16x8, lo8);
        bf16x8 bH = __builtin_bit_cast(bf16x8, *(const u16x8*)(WhiR + kk));
        bf16x8 bL = __builtin_bit_cast(bf16x8, *(const u16x8*)(WloR + kk));
        if (c & 1) {
            acc1 = __builtin_amdgcn_mfma_f32_16x16x32_bf16(aH, bH, acc1, 0, 0, 0);
            acc1 = __builtin_amdgcn_mfma_f32_16x16x32_bf16(aH, bL, acc1, 0, 0, 0);
            acc1 = __builtin_amdgcn_mfma_f32_16x16x32_bf16(aL, bH, acc1, 0, 0, 0);
        } else {
            acc0 = __builtin_amdgcn_mfma_f32_16x16x32_bf16(aH, bH, acc0, 0, 0, 0);
            acc0 = __builtin_amdgcn_mfma_f32_16x16x32_bf16(aH, bL, acc0, 0, 0, 0);
            acc0 = __builtin_amdgcn_mfma_f32_16x16x32_bf16(aL, bH, acc0, 0, 0, 0);
        }
    }
    f32x4 acc = acc0 + acc1;

    #pragma unroll
    for (int r = 0; r < 4; ++r) {
        int mm = m0 + wv * 16 + quad * 4 + r;
        out[(size_t)mm * Hh + (j0g + rw)] = acc[r] + bsum;
    }
}

// ---------------------------------------------------------------------------
// Recurrence: 256 wgs x 64 threads (1 wave). wg = (bg, jg): 16 b x 16 j tile.
// Wh j-slice resident in LDS hi/lo for the whole run. Per step, ZERO intra-wg
// barriers: full-K MFMA in-wave, epilogue straight from C-layout regs.
// h exchanged via double-buffered SEPARATE bf16 hi/lo arrays (no unpack on
// load path). Sync: per-wg monotonic flag slot, release store by lane 0
// (vmcnt-drained), 32-lane ballot poll with acquire loads. Deadlock-free:
// 256 one-wave wgs are trivially co-resident on 256 CUs.
// ---------------------------------------------------------------------------
__global__ __launch_bounds__(64) void rnn_mfma_kernel(
    const float* __restrict__ h0in, const float* __restrict__ Wh,
    float* __restrict__ out,
    unsigned short* __restrict__ hpk_hi, unsigned short* __restrict__ hpk_lo,
    unsigned* flags) {

    __shared__ unsigned short Whi[16 * 520];
    __shared__ unsigned short Wlo[16 * 520];

    const int lane = threadIdx.x;     // 0..63
    const int bg = blockIdx.x & 7;    // batch group (xcd-local under %8 rr)
    const int jg = blockIdx.x >> 3;   // j group
    const int b0g = bg * 16;
    const int j0g = jg * 16;

    // one-time: stage Wh rows j0g..j0g+15 into LDS hi/lo (RNE)
    #pragma unroll 4
    for (int it = 0; it < 32; ++it) {
        int idx = (it * 64 + lane) * 4;
        int j = idx >> 9;
        int k = idx & 511;
        float4 w = *(const float4*)(Wh + (size_t)(j0g + j) * Hh + k);
        int base = j * 520 + k;
        unsigned short s0 = f2bf_rne(w.x); Whi[base + 0] = s0; Wlo[base + 0] = f2bf_rne(w.x - bf2f(s0));
        unsigned short s1 = f2bf_rne(w.y); Whi[base + 1] = s1; Wlo[base + 1] = f2bf_rne(w.y - bf2f(s1));
        unsigned short s2 = f2bf_rne(w.z); Whi[base + 2] = s2; Wlo[base + 2] = f2bf_rne(w.z - bf2f(s2));
        unsigned short s3 = f2bf_rne(w.w); Whi[base + 3] = s3; Wlo[base + 3] = f2bf_rne(w.w - bf2f(s3));
    }
    __syncthreads();  // one-time only

    const int rw = lane & 15;
    const int quad = lane >> 4;
    const unsigned short* WhiR = Whi + rw * 520;
    const unsigned short* WloR = Wlo + rw * 520;

    for (int t = 0; t < Lt; ++t) {
        // prefetch xproj(+biases) for this step's outputs — independent of sync
        float xp[4];
        {
            size_t ob = ((size_t)t * Bn + (b0g + quad * 4)) * Hh + (j0g + rw);
            xp[0] = out[ob];
            xp[1] = out[ob + Hh];
            xp[2] = out[ob + 2 * Hh];
            xp[3] = out[ob + 3 * Hh];
        }

        if (t > 0) {
            unsigned tgt = (unsigned)t;
            while (true) {
                unsigned v = __hip_atomic_load(&flags[bg * 32 + (lane & 31)],
                                               __ATOMIC_ACQUIRE,
                                               __HIP_MEMORY_SCOPE_AGENT);
                if (__ballot(v >= tgt) == 0xFFFFFFFFFFFFFFFFull) break;
            }
        }

        f32x4 acc0 = {0.f, 0.f, 0.f, 0.f};
        f32x4 acc1 = {0.f, 0.f, 0.f, 0.f};
        const unsigned short* hhi =
            hpk_hi + (size_t)((t + 1) & 1) * (Bn * Hh) + (size_t)(b0g + rw) * Hh;
        const unsigned short* hlo =
            hpk_lo + (size_t)((t + 1) & 1) * (Bn * Hh) + (size_t)(b0g + rw) * Hh;

        #pragma unroll
        for (int c = 0; c < 16; ++c) {
            int kk = c * 32 + quad * 8;
            bf16x8 aH, aL;
            if (t == 0) {
                const float* hp = h0in + (size_t)(b0g + rw) * Hh + kk;
                float4 v0 = *(const float4*)hp;
                float4 v1 = *(const float4*)(hp + 4);
                float vv[8] = {v0.x, v0.y, v0.z, v0.w, v1.x, v1.y, v1.z, v1.w};
                u16x8 hi8, lo8;
                #pragma unroll
                for (int i = 0; i < 8; ++i) {
                    unsigned u = __float_as_uint(vv[i]);
                    unsigned short h = (unsigned short)(u >> 16);
                    hi8[i] = h;
                    lo8[i] = (unsigned short)(__float_as_uint(vv[i] - bf2f(h)) >> 16);
                }
                aH = __builtin_bit_cast(bf16x8, hi8);
                aL = __builtin_bit_cast(bf16x8, lo8);
            } else {
                aH = __builtin_bit_cast(bf16x8, *(const u16x8*)(hhi + kk));
                aL = __builtin_bit_cast(bf16x8, *(const u16x8*)(hlo + kk));
            }
            bf16x8 bH = __builtin_bit_cast(bf16x8, *(const u16x8*)(WhiR + kk));
            bf16x8 bL = __builtin_bit_cast(bf16x8, *(const u16x8*)(WloR + kk));
            if (c & 1) {
                acc1 = __builtin_amdgcn_mfma_f32_16x16x32_bf16(aH, bH, acc1, 0, 0, 0);
                acc1 = __builtin_amdgcn_mfma_f32_16x16x32_bf16(aH, bL, acc1, 0, 0, 0);
                acc1 = __builtin_amdgcn_mfma_f32_16x16x32_bf16(aL, bH, acc1, 0, 0, 0);
            } else {
                acc0 = __builtin_amdgcn_mfma_f32_16x16x32_bf16(aH, bH, acc0, 0, 0, 0);
                acc0 = __builtin_amdgcn_mfma_f32_16x16x32_bf16(aH, bL, acc0, 0, 0, 0);
                acc0 = __builtin_amdgcn_mfma_f32_16x16x32_bf16(aL, bH, acc0, 0, 0, 0);
            }
        }
        f32x4 acc = acc0 + acc1;

        // epilogue, wave-synchronous: col=lane&15 (j), row=quad*4+reg (b)
        unsigned short* shi = hpk_hi + (size_t)(t & 1) * (Bn * Hh);
        unsigned short* slo = hpk_lo + (size_t)(t & 1) * (Bn * Hh);
        #pragma unroll
        for (int r = 0; r < 4; ++r) {
            int b = b0g + quad * 4 + r;
            float hv = tanh_fast(acc[r] + xp[r]);
            size_t ob = ((size_t)t * Bn + b) * Hh + (j0g + rw);
            out[ob] = hv;
            if (t == Lt - 1) {
                out[(size_t)Lt * Bn * Hh + (size_t)b * Hh + (j0g + rw)] = hv;
            }
            unsigned u = __float_as_uint(hv);
            unsigned short hb = (unsigned short)(u >> 16);
            shi[(size_t)b * Hh + (j0g + rw)] = hb;
            slo[(size_t)b * Hh + (j0g + rw)] =
                (unsigned short)(__float_as_uint(hv - bf2f(hb)) >> 16);
        }

        if (t + 1 < Lt && lane == 0) {
            // release: compiler drains this wave's stores (vmcnt) + wbL2 first
            __hip_atomic_store(&flags[bg * 32 + jg], (unsigned)(t + 1),
                               __ATOMIC_RELEASE, __HIP_MEMORY_SCOPE_AGENT);
        }
    }
}

extern "C" void kernel_launch(void* const* d_in, const int* in_sizes, int n_in,
                              void* d_out, int out_size, void* d_ws, size_t ws_size,
                              hipStream_t stream) {
    const float* x    = (const float*)d_in[0];  // [L,B,D]
    const float* h0   = (const float*)d_in[1];  // [B,H]
    const float* Wx_w = (const float*)d_in[2];  // [H,D]
    const float* Wx_b = (const float*)d_in[3];  // [H]
    const float* Wh_w = (const float*)d_in[4];  // [H,H]
    const float* Wh_b = (const float*)d_in[5];  // [H]
    float* out = (float*)d_out;                 // hAll [L,B,H] ++ h_last [B,H]

    unsigned short* hpk_hi = (unsigned short*)d_ws;       // [2][B][H] bf16 hi
    unsigned short* hpk_lo = hpk_hi + 2 * Bn * Hh;        // [2][B][H] bf16 lo
    unsigned* flags = (unsigned*)(hpk_lo + 2 * Bn * Hh);  // [8][32] monotonic

    zero_flags_kernel<<<1, 256, 0, stream>>>(flags);
    xproj_mfma_kernel<<<(Lt * Bn / 64) * 32, 256, 0, stream>>>(x, Wx_w, Wx_b, Wh_b, out);
    rnn_mfma_kernel<<<256, 64, 0, stream>>>(h0, Wh_w, out, hpk_hi, hpk_lo, flags);
}

// Round 4
// 3072.832 us; speedup vs baseline: 2.1497x; 2.1497x over previous
//
#include <hip/hip_runtime.h>
#include <math.h>

#define Lt 512   // timesteps
#define Bn 128   // batch
#define Dd 512   // input dim
#define Hh 512   // hidden dim
#define BH (Bn * Hh)

typedef __attribute__((ext_vector_type(4))) float f32x4;
typedef __attribute__((ext_vector_type(8))) __bf16 bf16x8;
typedef __attribute__((ext_vector_type(8))) unsigned short u16x8;
typedef __attribute__((ext_vector_type(4))) unsigned int u32x4;

#define MFMA16 __builtin_amdgcn_mfma_f32_16x16x32_bf16

__device__ __forceinline__ float bf2f(unsigned short s) {
    return __uint_as_float(((unsigned)s) << 16);
}
__device__ __forceinline__ unsigned short f2bf_rne(float f) {
    unsigned u = __float_as_uint(f);
    u = (u + 0x7FFFu + ((u >> 16) & 1u)) >> 16;
    return (unsigned short)u;
}
// tanh via hw exp+rcp; saturates exactly at +/-1, NaN-free
__device__ __forceinline__ float tanh_fast(float z) {
    float e = __expf(2.f * z);
    return 1.f - 2.f * __builtin_amdgcn_rcpf(e + 1.f);
}
// result = (top16(b)<<16) | top16(a)   [element order: a then b, little-endian]
__device__ __forceinline__ unsigned pack_hi16(unsigned a, unsigned b) {
    return __builtin_amdgcn_perm(b, a, 0x07060302u);
}
// result = (low16(b)<<16) | low16(a)
__device__ __forceinline__ unsigned pack_lo16(unsigned a, unsigned b) {
    return __builtin_amdgcn_perm(b, a, 0x05040100u);
}

__global__ void zero_flags_kernel(unsigned* __restrict__ flags) {
    int i = blockIdx.x * 256 + threadIdx.x;
    if (i < 256) flags[i] = 0;
}

// stage 16 rows x 512 cols of W (row stride = `stride`) into LDS as bf16 hi/lo
__device__ __forceinline__ void stage_wslice(const float* __restrict__ W, int j0g,
                                             int stride, unsigned short* hiA,
                                             unsigned short* loA, int lane) {
    #pragma unroll 4
    for (int it = 0; it < 32; ++it) {
        int idx = (it * 64 + lane) * 4;
        int j = idx >> 9;
        int k = idx & 511;
        float4 w = *(const float4*)(W + (size_t)(j0g + j) * stride + k);
        int base = j * 520 + k;
        unsigned short s0 = f2bf_rne(w.x); hiA[base + 0] = s0; loA[base + 0] = f2bf_rne(w.x - bf2f(s0));
        unsigned short s1 = f2bf_rne(w.y); hiA[base + 1] = s1; loA[base + 1] = f2bf_rne(w.y - bf2f(s1));
        unsigned short s2 = f2bf_rne(w.z); hiA[base + 2] = s2; loA[base + 2] = f2bf_rne(w.z - bf2f(s2));
        unsigned short s3 = f2bf_rne(w.w); hiA[base + 3] = s3; loA[base + 3] = f2bf_rne(w.w - bf2f(s3));
    }
}

// ---------------------------------------------------------------------------
// Fused RNN: 256 wgs x 64 threads (1 wave). wg = (bg,jg): 16b x 16j tile.
// Per step: acc = x[t]*Wx^T (computed BEFORE the poll — overlaps handoff)
//           + h_{t-1}*Wh^T, then tanh(acc+bias).
// Wx & Wh j-slices LDS-resident hi/lo for the whole run (66.5 KB).
// Cross-wg h handoff: packed (hi16|lo16) u32 per element, double-buffered in
// d_ws, moved ONLY via relaxed agent atomics (sc1 -> IC-coherent, no
// buffer_inv/wbl2). Producer order: h stores -> s_waitcnt vmcnt(0) -> relaxed
// flag store. Consumer: relaxed ballot-poll, then relaxed u64 data loads
// (in-order issue after the poll branch). Deadlock-free: 256 one-wave wgs
// co-resident on 256 CUs. h0 published via a prologue round (flag value 1;
// step t waits >= t+1, releases t+2).
// ---------------------------------------------------------------------------
__global__ __launch_bounds__(64, 1) void rnn_fused_kernel(
    const float* __restrict__ x, const float* __restrict__ h0in,
    const float* __restrict__ Wx, const float* __restrict__ bx,
    const float* __restrict__ Wh, const float* __restrict__ bh,
    float* __restrict__ out, unsigned* __restrict__ hpk, unsigned* flags) {

    __shared__ unsigned short WxHi[16 * 520], WxLo[16 * 520];
    __shared__ unsigned short WhHi[16 * 520], WhLo[16 * 520];

    const int lane = threadIdx.x;
    const int bg = blockIdx.x & 7;    // same bg -> same XCD under rr dispatch
    const int jg = blockIdx.x >> 3;
    const int b0g = bg * 16;
    const int j0g = jg * 16;

    stage_wslice(Wx, j0g, Dd, WxHi, WxLo, lane);
    stage_wslice(Wh, j0g, Hh, WhHi, WhLo, lane);
    __syncthreads();  // one-time only

    const int rw = lane & 15;
    const int quad = lane >> 4;
    const unsigned short* WxHiR = WxHi + rw * 520;
    const unsigned short* WxLoR = WxLo + rw * 520;
    const unsigned short* WhHiR = WhHi + rw * 520;
    const unsigned short* WhLoR = WhLo + rw * 520;
    const float bsum = bx[j0g + rw] + bh[j0g + rw];

    // ---- prologue: publish h0 tile into buf1 (read by step 0) ----
    #pragma unroll
    for (int r = 0; r < 4; ++r) {
        int b = b0g + quad * 4 + r;
        float v = h0in[(size_t)b * Hh + (j0g + rw)];
        unsigned u = __float_as_uint(v);
        unsigned hb = u >> 16;  // trunc split
        unsigned lb = __float_as_uint(v - __uint_as_float(u & 0xFFFF0000u)) >> 16;
        __hip_atomic_store(hpk + BH + (size_t)b * Hh + (j0g + rw),
                           (hb << 16) | lb, __ATOMIC_RELAXED,
                           __HIP_MEMORY_SCOPE_AGENT);
    }
    asm volatile("s_waitcnt vmcnt(0)" ::: "memory");
    if (lane == 0) {
        __hip_atomic_store(&flags[bg * 32 + jg], 1u, __ATOMIC_RELAXED,
                           __HIP_MEMORY_SCOPE_AGENT);
    }

    for (int t = 0; t < Lt; ++t) {
        f32x4 aHH = {0.f, 0.f, 0.f, 0.f};
        f32x4 aHL = {0.f, 0.f, 0.f, 0.f};
        f32x4 aLH = {0.f, 0.f, 0.f, 0.f};

        // ---- xp phase: x[t] * Wx^T — independent of sync, overlaps handoff --
        const float* xrow = x + ((size_t)t * Bn + (b0g + rw)) * Dd;
        #pragma unroll
        for (int c = 0; c < 16; ++c) {
            int kk = c * 32 + quad * 8;
            float4 v0 = *(const float4*)(xrow + kk);
            float4 v1 = *(const float4*)(xrow + kk + 4);
            unsigned u0 = __float_as_uint(v0.x), u1 = __float_as_uint(v0.y);
            unsigned u2 = __float_as_uint(v0.z), u3 = __float_as_uint(v0.w);
            unsigned u4 = __float_as_uint(v1.x), u5 = __float_as_uint(v1.y);
            unsigned u6 = __float_as_uint(v1.z), u7 = __float_as_uint(v1.w);
            u32x4 hi4 = {pack_hi16(u0, u1), pack_hi16(u2, u3),
                         pack_hi16(u4, u5), pack_hi16(u6, u7)};
            float l0 = v0.x - __uint_as_float(u0 & 0xFFFF0000u);
            float l1 = v0.y - __uint_as_float(u1 & 0xFFFF0000u);
            float l2 = v0.z - __uint_as_float(u2 & 0xFFFF0000u);
            float l3 = v0.w - __uint_as_float(u3 & 0xFFFF0000u);
            float l4 = v1.x - __uint_as_float(u4 & 0xFFFF0000u);
            float l5 = v1.y - __uint_as_float(u5 & 0xFFFF0000u);
            float l6 = v1.z - __uint_as_float(u6 & 0xFFFF0000u);
            float l7 = v1.w - __uint_as_float(u7 & 0xFFFF0000u);
            u32x4 lo4 = {pack_hi16(__float_as_uint(l0), __float_as_uint(l1)),
                         pack_hi16(__float_as_uint(l2), __float_as_uint(l3)),
                         pack_hi16(__float_as_uint(l4), __float_as_uint(l5)),
                         pack_hi16(__float_as_uint(l6), __float_as_uint(l7))};
            bf16x8 aH = __builtin_bit_cast(bf16x8, hi4);
            bf16x8 aL = __builtin_bit_cast(bf16x8, lo4);
            bf16x8 bH = __builtin_bit_cast(bf16x8, *(const u16x8*)(WxHiR + kk));
            bf16x8 bL = __builtin_bit_cast(bf16x8, *(const u16x8*)(WxLoR + kk));
            aHH = MFMA16(aH, bH, aHH, 0, 0, 0);
            aHL = MFMA16(aH, bL, aHL, 0, 0, 0);
            aLH = MFMA16(aL, bH, aLH, 0, 0, 0);
        }

        // ---- wait for h_{t-1}: all 32 producers of this bg ----
        {
            const unsigned tgt = (unsigned)t + 1u;
            while (true) {
                unsigned v = __hip_atomic_load(&flags[bg * 32 + (lane & 31)],
                                               __ATOMIC_RELAXED,
                                               __HIP_MEMORY_SCOPE_AGENT);
                if (__ballot(v >= tgt) == 0xFFFFFFFFFFFFFFFFull) break;
            }
        }

        // ---- h phase: h_{t-1} * Wh^T ----
        const unsigned* hrow =
            hpk + (size_t)((t + 1) & 1) * BH + (size_t)(b0g + rw) * Hh;
        #pragma unroll
        for (int c = 0; c < 16; ++c) {
            int kk = c * 32 + quad * 8;
            unsigned long long p0 = __hip_atomic_load(
                (const unsigned long long*)(hrow + kk + 0),
                __ATOMIC_RELAXED, __HIP_MEMORY_SCOPE_AGENT);
            unsigned long long p1 = __hip_atomic_load(
                (const unsigned long long*)(hrow + kk + 2),
                __ATOMIC_RELAXED, __HIP_MEMORY_SCOPE_AGENT);
            unsigned long long p2 = __hip_atomic_load(
                (const unsigned long long*)(hrow + kk + 4),
                __ATOMIC_RELAXED, __HIP_MEMORY_SCOPE_AGENT);
            unsigned long long p3 = __hip_atomic_load(
                (const unsigned long long*)(hrow + kk + 6),
                __ATOMIC_RELAXED, __HIP_MEMORY_SCOPE_AGENT);
            unsigned q0 = (unsigned)p0, q1 = (unsigned)(p0 >> 32);
            unsigned q2 = (unsigned)p1, q3 = (unsigned)(p1 >> 32);
            unsigned q4 = (unsigned)p2, q5 = (unsigned)(p2 >> 32);
            unsigned q6 = (unsigned)p3, q7 = (unsigned)(p3 >> 32);
            u32x4 hi4 = {pack_hi16(q0, q1), pack_hi16(q2, q3),
                         pack_hi16(q4, q5), pack_hi16(q6, q7)};
            u32x4 lo4 = {pack_lo16(q0, q1), pack_lo16(q2, q3),
                         pack_lo16(q4, q5), pack_lo16(q6, q7)};
            bf16x8 aH = __builtin_bit_cast(bf16x8, hi4);
            bf16x8 aL = __builtin_bit_cast(bf16x8, lo4);
            bf16x8 bH = __builtin_bit_cast(bf16x8, *(const u16x8*)(WhHiR + kk));
            bf16x8 bL = __builtin_bit_cast(bf16x8, *(const u16x8*)(WhLoR + kk));
            aHH = MFMA16(aH, bH, aHH, 0, 0, 0);
            aHL = MFMA16(aH, bL, aHL, 0, 0, 0);
            aLH = MFMA16(aL, bH, aLH, 0, 0, 0);
        }

        f32x4 acc = aHH + aHL + aLH;

        // ---- epilogue: C/D layout col=lane&15 (j), row=quad*4+r (b) ----
        float hv[4];
        #pragma unroll
        for (int r = 0; r < 4; ++r) hv[r] = tanh_fast(acc[r] + bsum);

        unsigned* hw = hpk + (size_t)(t & 1) * BH;
        #pragma unroll
        for (int r = 0; r < 4; ++r) {
            int b = b0g + quad * 4 + r;
            unsigned u = __float_as_uint(hv[r]);
            unsigned hb = u >> 16;
            unsigned lb =
                __float_as_uint(hv[r] - __uint_as_float(u & 0xFFFF0000u)) >> 16;
            __hip_atomic_store(hw + (size_t)b * Hh + (j0g + rw), (hb << 16) | lb,
                               __ATOMIC_RELAXED, __HIP_MEMORY_SCOPE_AGENT);
        }
        asm volatile("s_waitcnt vmcnt(0)" ::: "memory");
        if (lane == 0 && t + 1 < Lt) {
            __hip_atomic_store(&flags[bg * 32 + jg], (unsigned)(t + 2),
                               __ATOMIC_RELAXED, __HIP_MEMORY_SCOPE_AGENT);
        }

        // out stores after the flag — not on anyone's critical path
        #pragma unroll
        for (int r = 0; r < 4; ++r) {
            int b = b0g + quad * 4 + r;
            out[((size_t)t * Bn + b) * Hh + (j0g + rw)] = hv[r];
        }
        if (t == Lt - 1) {
            #pragma unroll
            for (int r = 0; r < 4; ++r) {
                int b = b0g + quad * 4 + r;
                out[(size_t)Lt * BH + (size_t)b * Hh + (j0g + rw)] = hv[r];
            }
        }
    }
}

extern "C" void kernel_launch(void* const* d_in, const int* in_sizes, int n_in,
                              void* d_out, int out_size, void* d_ws, size_t ws_size,
                              hipStream_t stream) {
    const float* x    = (const float*)d_in[0];  // [L,B,D]
    const float* h0   = (const float*)d_in[1];  // [B,H]
    const float* Wx_w = (const float*)d_in[2];  // [H,D]
    const float* Wx_b = (const float*)d_in[3];  // [H]
    const float* Wh_w = (const float*)d_in[4];  // [H,H]
    const float* Wh_b = (const float*)d_in[5];  // [H]
    float* out = (float*)d_out;                 // hAll [L,B,H] ++ h_last [B,H]

    unsigned* hpk   = (unsigned*)d_ws;          // 2 x [B][H] packed (hi|lo), 512 KB
    unsigned* flags = hpk + 2 * BH;             // [8][32] monotonic counters

    zero_flags_kernel<<<1, 256, 0, stream>>>(flags);
    rnn_fused_kernel<<<256, 64, 0, stream>>>(x, h0, Wx_w, Wx_b, Wh_w, Wh_b,
                                             out, hpk, flags);
}